// Round 1
// 1174.475 us; speedup vs baseline: 1.0164x; 1.0164x over previous
//
#include <hip/hip_runtime.h>
#include <stdint.h>

// Problem constants (fixed by the reference)
#define TAUF 0.1f
#define MIN_SCOREF 0.5f
#define KTOP 256
#define BASE 130
#define BASE2 16900
#define TABLE_N 4394000   // 260*130*130 covers all neighbor keys
#define NEGF (-1e30f)
#define CAP2 3072
#define NSMAX 4096
#define ROWS_PB 192
#define CHUNK 32

// ---------------------------------------------------------------- build table
__global__ void k_build(const int* __restrict__ coords, int* __restrict__ table,
                        int* __restrict__ keys, int n) {
  int i = blockIdx.x * 256 + threadIdx.x;
  if (i >= n) return;
  int4 c = ((const int4*)coords)[i];
  int key = (c.x * BASE + c.y + 1) * BASE2 + (c.z + 1) * BASE + (c.w + 1);
  keys[i] = key;
  table[key] = i;   // keys are unique (coords sampled without replacement)
}

// ---------------------------------------------------------------- peak detect
// Also builds the 2048-bin score histogram (bucket over float bits in [0.5,1])
// so k_select only needs one pass over the candidate array.
__global__ void k_peak(const float* __restrict__ scores, const int* __restrict__ keys,
                       const int* __restrict__ table, uint2* __restrict__ cand,
                       int* __restrict__ cand_cnt, int* __restrict__ hist, int n) {
  int i = blockIdx.x * 256 + threadIdx.x;
  if (i >= n) return;
  float s = scores[i];
  if (!(s > TAUF)) return;
  int key = keys[i];
  const int dk[7] = {-BASE2, -BASE, -1, 0, 1, BASE, BASE2};
  float nm = NEGF;
#pragma unroll
  for (int o = 0; o < 7; ++o) {
    int j = table[key + dk[o]];
    if (j >= 0) {
      float sj = scores[j];
      if (sj > TAUF) nm = fmaxf(nm, sj);
    }
  }
  if (s >= nm - 1e-6f && s >= MIN_SCOREF) {
    int p = atomicAdd(cand_cnt, 1);
    if (p < n) cand[p] = make_uint2(__float_as_uint(s), (unsigned)i);
    unsigned sb = __float_as_uint(s);
    int b = (int)((sb - 0x3F000000u) >> 12);
    b = min(max(b, 0), 2047);
    atomicAdd(&hist[b], 1);
  }
}

// ------------------------------------------------- top-K select (one block)
// Uses the precomputed histogram to find the boundary bucket, compacts the
// boundary set in ONE pass over cand, then bitonic-sorts only the next
// power-of-two >= m (typically ~512, not 4096). Key packs
// (score_bits<<32)|~idx to match lax.top_k's stable tie-break.
__global__ __launch_bounds__(1024) void k_select(const uint2* __restrict__ cand,
                                                 const int* __restrict__ cand_cnt,
                                                 const int* __restrict__ hist,
                                                 float* __restrict__ conf_out,
                                                 int* __restrict__ owner_init,
                                                 int* __restrict__ peak_vox) {
  __shared__ int hist_s[2048];
  __shared__ int part[64];
  __shared__ unsigned long long keys_s[NSMAX];
  __shared__ int bstar_s, m_s;
  int t = threadIdx.x;
  int nc = *cand_cnt;
  for (int b = t; b < 2048; b += 1024) hist_s[b] = hist[b];
  if (t == 0) m_s = 0;
  __syncthreads();
  if (t < 64) {
    int acc = 0;
    for (int b = t * 32; b < t * 32 + 32; ++b) acc += hist_s[b];
    part[t] = acc;
  }
  __syncthreads();
  if (t == 0) {
    int target = min(nc, KTOP);
    int bs = 0;
    if (target > 0) {
      int run = 0, w = 63;
      for (; w >= 0; --w) {
        if (run + part[w] >= target) break;
        run += part[w];
      }
      if (w < 0) {
        bs = 0;
      } else {
        for (int b = w * 32 + 31;; --b) {
          run += hist_s[b];
          if (run >= target || b == w * 32) { bs = b; break; }
        }
      }
    }
    bstar_s = bs;
  }
  __syncthreads();
  int bs = bstar_s;
  for (int idx = t; idx < nc; idx += 1024) {
    uint2 cv = cand[idx];
    int b = (int)((cv.x - 0x3F000000u) >> 12);
    b = min(max(b, 0), 2047);
    if (b >= bs) {
      int p = atomicAdd(&m_s, 1);
      if (p < CAP2)
        keys_s[p] = ((unsigned long long)cv.x << 32) | (unsigned)(~cv.y);
    }
  }
  __syncthreads();
  int m = min(m_s, CAP2);
  int ns = 256;
  while (ns < m) ns <<= 1;          // pow2 >= max(m,256), <= 4096
  for (int idx = t; idx < ns; idx += 1024)
    if (idx >= m) keys_s[idx] = 0ULL;
  __syncthreads();
  // bitonic sort, descending, over ns elements only
  for (int k2 = 2; k2 <= ns; k2 <<= 1) {
    for (int j2 = k2 >> 1; j2 > 0; j2 >>= 1) {
      for (int i = t; i < ns; i += 1024) {
        int ixj = i ^ j2;
        if (ixj > i) {
          unsigned long long a = keys_s[i], b = keys_s[ixj];
          bool descSeg = ((i & k2) == 0);
          bool sw = descSeg ? (a < b) : (a > b);
          if (sw) { keys_s[i] = b; keys_s[ixj] = a; }
        }
      }
      __syncthreads();
    }
  }
  if (t < KTOP) {
    int navail = min(nc, KTOP);
    if (t < navail) {
      unsigned long long kk = keys_s[t];
      float sc = __uint_as_float((unsigned)(kk >> 32));
      int vi = (int)(~(unsigned)(kk & 0xFFFFFFFFu));
      conf_out[t] = sc;
      owner_init[vi] = t;
      peak_vox[t] = vi;
    } else {
      conf_out[t] = 0.0f;
      peak_vox[t] = -1;
    }
  }
}

// ------------------------------------- owner assignment + segment sums
__global__ void k_owner(const float* __restrict__ scores, const int* __restrict__ keys,
                        const int* __restrict__ table, const int* __restrict__ owner_init,
                        const int* __restrict__ peak_vox, int* __restrict__ visited,
                        const float* __restrict__ feats, float* __restrict__ sums,
                        float* __restrict__ counts) {
  int t = blockIdx.x * blockDim.x + threadIdx.x;
  if (t >= KTOP * 7) return;
  int p = t / 7, o = t % 7;
  int v0 = peak_vox[p];
  if (v0 < 0) return;
  const int dk[7] = {-BASE2, -BASE, -1, 0, 1, BASE, BASE2};
  int v = table[keys[v0] + dk[o]];
  if (v < 0) return;
  if (!(scores[v] > TAUF)) return;            // mask[v]
  int kv = keys[v];
  int own = -1;
#pragma unroll
  for (int oo = 0; oo < 7; ++oo) {
    int j = table[kv + dk[oo]];
    if (j >= 0 && scores[j] > TAUF) own = max(own, owner_init[j]);
  }
  if (own < 0) return;
  if (atomicCAS(&visited[v], 0, 1) == 0) {
    atomicAdd(&counts[own], 1.0f);
    const float* fv = feats + (size_t)v * 128;
    float* so = sums + own * 128;
    for (int d = 0; d < 128; ++d) atomicAdd(&so[d], fv[d]);
  }
}

// ----------------------------- cols^T (32 x 257): col 0 = bg, col 1+p = conf*(mean@Wc+bc)
__global__ void k_cols(const float* __restrict__ sums, const float* __restrict__ counts,
                       const float* __restrict__ conf, const float* __restrict__ Wc,
                       const float* __restrict__ bc, const float* __restrict__ bg,
                       float* __restrict__ colsT) {
  int gid = blockIdx.x * blockDim.x + threadIdx.x;
  if (gid >= 32 * 257) return;
  int kd = gid / 257, jo = gid % 257;
  float val;
  if (jo == 0) {
    val = bg[kd];
  } else {
    int p = jo - 1;
    float inv = 1.0f / fmaxf(counts[p], 1.0f);
    float acc = bc[kd];
    const float* sp = sums + p * 128;
    for (int c = 0; c < 128; ++c) acc += sp[c] * inv * Wc[c * 32 + kd];
    val = conf[p] * acc;
  }
  colsT[kd * 257 + jo] = val;
}

// ----------------------------- fused: out = (feats @ Wv + bv) @ colsT
// Per 192-row block, loop 32-row chunks: stage feats -> desc chunk in LDS ->
// multiply by colsT. Removes the N x 32 desc buffer round-trip (128 MB HBM).
// Accumulation order identical to the previous split kernels (c=0..127 then
// k=0..31 ascending), so results are bitwise-identical.
__global__ __launch_bounds__(256) void k_go(const float* __restrict__ feats,
                                            const float* __restrict__ Wv,
                                            const float* __restrict__ bv,
                                            const float* __restrict__ colsT,
                                            float* __restrict__ out, int n) {
  __shared__ __align__(16) float Wv_s[128 * 32];    // 16.0 KB
  __shared__ __align__(16) float cols_s[32 * 260];  // 33.3 KB (pad 260)
  __shared__ __align__(16) float feats_s[CHUNK * 129]; // 16.5 KB (pad 129)
  __shared__ float desc_s[CHUNK * 33];              // 4.2 KB (pad 33)
  __shared__ float bv_s[32];
  // total ~70.4 KB -> 2 blocks/CU
  int t = threadIdx.x;
  int rbase = blockIdx.x * ROWS_PB;
  {
    const float4* src = (const float4*)Wv;
    float4* dst = (float4*)Wv_s;
    for (int i = t; i < 1024; i += 256) dst[i] = src[i];
  }
  for (int idx = t; idx < 32 * 257; idx += 256) {
    int kd = idx / 257, jo = idx % 257;
    cols_s[kd * 260 + jo] = colsT[idx];
  }
  if (t < 32) bv_s[t] = bv[t];

  for (int c0 = 0; c0 < ROWS_PB; c0 += CHUNK) {
    __syncthreads();   // feats_s/desc_s free; also covers Wv_s/cols_s staging
    // P1: stage 32x128 feats chunk (coalesced float4)
    {
      int idx = t;
      for (int it = 0; it < 4; ++it, idx += 256) {
        int r = idx >> 5, q = idx & 31;
        int row = rbase + c0 + r;
        float4 v = make_float4(0.f, 0.f, 0.f, 0.f);
        if (row < n) v = *(const float4*)(feats + (size_t)row * 128 + q * 4);
        float* fd = &feats_s[r * 129 + q * 4];
        fd[0] = v.x; fd[1] = v.y; fd[2] = v.z; fd[3] = v.w;
      }
    }
    __syncthreads();
    // P2: desc chunk = feats_chunk @ Wv + bv ; thread -> (r = t&31, k0 = (t>>5)*4)
    {
      int r = t & 31, k0 = (t >> 5) * 4;
      float a0 = bv_s[k0], a1 = bv_s[k0 + 1], a2 = bv_s[k0 + 2], a3 = bv_s[k0 + 3];
      const float* fr = &feats_s[r * 129];
#pragma unroll 8
      for (int c = 0; c < 128; ++c) {
        float f = fr[c];
        float4 w = *(const float4*)&Wv_s[c * 32 + k0];
        a0 += f * w.x; a1 += f * w.y; a2 += f * w.z; a3 += f * w.w;
      }
      float* dd = &desc_s[r * 33 + k0];
      dd[0] = a0; dd[1] = a1; dd[2] = a2; dd[3] = a3;
    }
    __syncthreads();
    // P3: out rows = desc_chunk @ cols_s ; thread -> (row rg = t>>3, jg = t&7)
    {
      int rg = t >> 3, jg = t & 7;
      int row = rbase + c0 + rg;
      if (row < n) {
        float dreg[32];
#pragma unroll
        for (int k = 0; k < 32; ++k) dreg[k] = desc_s[rg * 33 + k];
        float* op = out + 256 + (size_t)row * 257;
        for (int jc = 0; jc < 4; ++jc) {
          int j0 = jc * 64 + jg * 8;
          float acc[8];
#pragma unroll
          for (int j = 0; j < 8; ++j) acc[j] = 0.f;
#pragma unroll 4
          for (int k = 0; k < 32; ++k) {
            float f = dreg[k];
            float4 cA = *(const float4*)&cols_s[k * 260 + j0];
            float4 cB = *(const float4*)&cols_s[k * 260 + j0 + 4];
            acc[0] += f * cA.x; acc[1] += f * cA.y; acc[2] += f * cA.z; acc[3] += f * cA.w;
            acc[4] += f * cB.x; acc[5] += f * cB.y; acc[6] += f * cB.z; acc[7] += f * cB.w;
          }
#pragma unroll
          for (int j = 0; j < 8; ++j) op[j0 + j] = acc[j];
        }
        if (jg == 0) {   // tail column jo = 256
          float accT = 0.f;
#pragma unroll 8
          for (int k = 0; k < 32; ++k) accT += dreg[k] * cols_s[k * 260 + 256];
          op[256] = accT;
        }
      }
    }
  }
}

// ---------------------------------------------------------------------------
extern "C" void kernel_launch(void* const* d_in, const int* in_sizes, int n_in,
                              void* d_out, int out_size, void* d_ws, size_t ws_size,
                              hipStream_t stream) {
  const int*   coords = (const int*)d_in[0];
  const float* feats  = (const float*)d_in[1];
  const float* scores = (const float*)d_in[2];
  const float* Wv     = (const float*)d_in[3];
  const float* bv     = (const float*)d_in[4];
  const float* Wc     = (const float*)d_in[5];
  const float* bc     = (const float*)d_in[6];
  const float* bg     = (const float*)d_in[7];
  float* out = (float*)d_out;
  int n = in_sizes[0] / 4;

  char* ws = (char*)d_ws;
  size_t off = 0;
  auto alloc = [&](size_t bytes) -> char* {
    char* p = ws + off;
    off = (off + bytes + 255) & ~(size_t)255;
    return p;
  };
  // 0xFF region (contiguous from ws start): table + owner_init
  int*   table      = (int*)alloc((size_t)TABLE_N * 4);
  int*   owner_init = (int*)alloc((size_t)n * 4);
  size_t ff_bytes   = off;
  int*   keys       = (int*)alloc((size_t)n * 4);
  // zero region (contiguous)
  char*  zero_base  = ws + off;
  int*   visited    = (int*)alloc((size_t)n * 4);
  int*   cand_cnt   = (int*)alloc(256);
  int*   hist       = (int*)alloc(2048 * 4);
  float* sums       = (float*)alloc(256 * 128 * 4);
  float* counts     = (float*)alloc(256 * 4);
  size_t zero_bytes = (size_t)((ws + off) - zero_base);
  uint2* cand       = (uint2*)alloc((size_t)n * 8);
  int*   peak_vox   = (int*)alloc(KTOP * 4);
  float* colsT      = (float*)alloc(32 * 257 * 4);
  (void)ws_size;

  hipMemsetAsync(table, 0xFF, ff_bytes, stream);
  hipMemsetAsync(zero_base, 0, zero_bytes, stream);

  int nb = (n + 255) / 256;
  k_build<<<nb, 256, 0, stream>>>(coords, table, keys, n);
  k_peak<<<nb, 256, 0, stream>>>(scores, keys, table, cand, cand_cnt, hist, n);
  k_select<<<1, 1024, 0, stream>>>(cand, cand_cnt, hist, out, owner_init, peak_vox);
  k_owner<<<7, 256, 0, stream>>>(scores, keys, table, owner_init, peak_vox,
                                 visited, feats, sums, counts);
  k_cols<<<(32 * 257 + 255) / 256, 256, 0, stream>>>(sums, counts, out, Wc, bc, bg, colsT);
  k_go<<<(n + ROWS_PB - 1) / ROWS_PB, 256, 0, stream>>>(feats, Wv, bv, colsT, out, n);
}

// Round 2
// 1125.745 us; speedup vs baseline: 1.0604x; 1.0433x over previous
//
#include <hip/hip_runtime.h>
#include <stdint.h>

// Problem constants (fixed by the reference)
#define TAUF 0.1f
#define MIN_SCOREF 0.5f
#define KTOP 256
#define BASE 130
#define BASE2 16900
#define TABLE_N 4394000   // 260*130*130 covers all neighbor keys
#define NEGF (-1e30f)
#define CAP2 3072
#define NSMAX 4096

// ---------------------------------------------------------------- build table
__global__ void k_build(const int* __restrict__ coords, int* __restrict__ table,
                        int* __restrict__ keys, int n) {
  int i = blockIdx.x * 256 + threadIdx.x;
  if (i >= n) return;
  int4 c = ((const int4*)coords)[i];
  int key = (c.x * BASE + c.y + 1) * BASE2 + (c.z + 1) * BASE + (c.w + 1);
  keys[i] = key;
  table[key] = i;   // keys are unique (coords sampled without replacement)
}

// ---------------------------------------------------------------- peak detect
// Also builds the 2048-bin score histogram (bucket over float bits in [0.5,1])
// so k_select only needs one pass over the candidate array.
__global__ void k_peak(const float* __restrict__ scores, const int* __restrict__ keys,
                       const int* __restrict__ table, uint2* __restrict__ cand,
                       int* __restrict__ cand_cnt, int* __restrict__ hist, int n) {
  int i = blockIdx.x * 256 + threadIdx.x;
  if (i >= n) return;
  float s = scores[i];
  if (!(s > TAUF)) return;
  int key = keys[i];
  const int dk[7] = {-BASE2, -BASE, -1, 0, 1, BASE, BASE2};
  float nm = NEGF;
#pragma unroll
  for (int o = 0; o < 7; ++o) {
    int j = table[key + dk[o]];
    if (j >= 0) {
      float sj = scores[j];
      if (sj > TAUF) nm = fmaxf(nm, sj);
    }
  }
  if (s >= nm - 1e-6f && s >= MIN_SCOREF) {
    int p = atomicAdd(cand_cnt, 1);
    if (p < n) cand[p] = make_uint2(__float_as_uint(s), (unsigned)i);
    unsigned sb = __float_as_uint(s);
    int b = (int)((sb - 0x3F000000u) >> 12);
    b = min(max(b, 0), 2047);
    atomicAdd(&hist[b], 1);
  }
}

// ------------------------------------------------- top-K select (one block)
__global__ __launch_bounds__(1024) void k_select(const uint2* __restrict__ cand,
                                                 const int* __restrict__ cand_cnt,
                                                 const int* __restrict__ hist,
                                                 float* __restrict__ conf_out,
                                                 int* __restrict__ owner_init,
                                                 int* __restrict__ peak_vox) {
  __shared__ int hist_s[2048];
  __shared__ int part[64];
  __shared__ unsigned long long keys_s[NSMAX];
  __shared__ int bstar_s, m_s;
  int t = threadIdx.x;
  int nc = *cand_cnt;
  for (int b = t; b < 2048; b += 1024) hist_s[b] = hist[b];
  if (t == 0) m_s = 0;
  __syncthreads();
  if (t < 64) {
    int acc = 0;
    for (int b = t * 32; b < t * 32 + 32; ++b) acc += hist_s[b];
    part[t] = acc;
  }
  __syncthreads();
  if (t == 0) {
    int target = min(nc, KTOP);
    int bs = 0;
    if (target > 0) {
      int run = 0, w = 63;
      for (; w >= 0; --w) {
        if (run + part[w] >= target) break;
        run += part[w];
      }
      if (w < 0) {
        bs = 0;
      } else {
        for (int b = w * 32 + 31;; --b) {
          run += hist_s[b];
          if (run >= target || b == w * 32) { bs = b; break; }
        }
      }
    }
    bstar_s = bs;
  }
  __syncthreads();
  int bs = bstar_s;
  for (int idx = t; idx < nc; idx += 1024) {
    uint2 cv = cand[idx];
    int b = (int)((cv.x - 0x3F000000u) >> 12);
    b = min(max(b, 0), 2047);
    if (b >= bs) {
      int p = atomicAdd(&m_s, 1);
      if (p < CAP2)
        keys_s[p] = ((unsigned long long)cv.x << 32) | (unsigned)(~cv.y);
    }
  }
  __syncthreads();
  int m = min(m_s, CAP2);
  int ns = 256;
  while (ns < m) ns <<= 1;          // pow2 >= max(m,256), <= 4096
  for (int idx = t; idx < ns; idx += 1024)
    if (idx >= m) keys_s[idx] = 0ULL;
  __syncthreads();
  // bitonic sort, descending, over ns elements only
  for (int k2 = 2; k2 <= ns; k2 <<= 1) {
    for (int j2 = k2 >> 1; j2 > 0; j2 >>= 1) {
      for (int i = t; i < ns; i += 1024) {
        int ixj = i ^ j2;
        if (ixj > i) {
          unsigned long long a = keys_s[i], b = keys_s[ixj];
          bool descSeg = ((i & k2) == 0);
          bool sw = descSeg ? (a < b) : (a > b);
          if (sw) { keys_s[i] = b; keys_s[ixj] = a; }
        }
      }
      __syncthreads();
    }
  }
  if (t < KTOP) {
    int navail = min(nc, KTOP);
    if (t < navail) {
      unsigned long long kk = keys_s[t];
      float sc = __uint_as_float((unsigned)(kk >> 32));
      int vi = (int)(~(unsigned)(kk & 0xFFFFFFFFu));
      conf_out[t] = sc;
      owner_init[vi] = t;
      peak_vox[t] = vi;
    } else {
      conf_out[t] = 0.0f;
      peak_vox[t] = -1;
    }
  }
}

// ------------------------------------- owner assignment + segment sums
__global__ void k_owner(const float* __restrict__ scores, const int* __restrict__ keys,
                        const int* __restrict__ table, const int* __restrict__ owner_init,
                        const int* __restrict__ peak_vox, int* __restrict__ visited,
                        const float* __restrict__ feats, float* __restrict__ sums,
                        float* __restrict__ counts) {
  int t = blockIdx.x * blockDim.x + threadIdx.x;
  if (t >= KTOP * 7) return;
  int p = t / 7, o = t % 7;
  int v0 = peak_vox[p];
  if (v0 < 0) return;
  const int dk[7] = {-BASE2, -BASE, -1, 0, 1, BASE, BASE2};
  int v = table[keys[v0] + dk[o]];
  if (v < 0) return;
  if (!(scores[v] > TAUF)) return;            // mask[v]
  int kv = keys[v];
  int own = -1;
#pragma unroll
  for (int oo = 0; oo < 7; ++oo) {
    int j = table[kv + dk[oo]];
    if (j >= 0 && scores[j] > TAUF) own = max(own, owner_init[j]);
  }
  if (own < 0) return;
  if (atomicCAS(&visited[v], 0, 1) == 0) {
    atomicAdd(&counts[own], 1.0f);
    const float* fv = feats + (size_t)v * 128;
    float* so = sums + own * 128;
    for (int d = 0; d < 128; ++d) atomicAdd(&so[d], fv[d]);
  }
}

// ----------------------------- cols^T (32 x 257): col 0 = bg, col 1+p = conf*(mean@Wc+bc)
__global__ void k_cols(const float* __restrict__ sums, const float* __restrict__ counts,
                       const float* __restrict__ conf, const float* __restrict__ Wc,
                       const float* __restrict__ bc, const float* __restrict__ bg,
                       float* __restrict__ colsT) {
  int gid = blockIdx.x * blockDim.x + threadIdx.x;
  if (gid >= 32 * 257) return;
  int kd = gid / 257, jo = gid % 257;
  float val;
  if (jo == 0) {
    val = bg[kd];
  } else {
    int p = jo - 1;
    float inv = 1.0f / fmaxf(counts[p], 1.0f);
    float acc = bc[kd];
    const float* sp = sums + p * 128;
    for (int c = 0; c < 128; ++c) acc += sp[c] * inv * Wc[c * 32 + kd];
    val = conf[p] * acc;
  }
  colsT[kd * 257 + jo] = val;
}

// ----------------------------- fused row kernel: out = (feats @ Wv + bv) @ colsT
// One row per thread. Wv/colsT live in LDS and are read at wave-uniform
// addresses (pure broadcast, conflict-free). desc lives in registers. No
// barriers after the initial staging -> latency hidden by TLP/ILP instead of
// being exposed at per-chunk syncs. Accumulation order identical to the
// previous kernels (c=0..127 ascending into bv-init acc; k=0..31 ascending
// from zero), so results are bitwise-identical.
__global__ __launch_bounds__(256) void k_rows(const float* __restrict__ feats,
                                              const float* __restrict__ Wv,
                                              const float* __restrict__ bv,
                                              const float* __restrict__ colsT,
                                              float* __restrict__ out, int n) {
  __shared__ __align__(16) float Wv_s[128 * 32];    // 16.0 KB
  __shared__ __align__(16) float cols_s[32 * 260];  // 33.3 KB (stride 260: b128-aligned)
  __shared__ float bv_s[32];
  // total ~49.8 KB -> 3 blocks/CU (12 waves)
  int t = threadIdx.x;
  {
    const float4* src = (const float4*)Wv;
    float4* dst = (float4*)Wv_s;
    for (int i = t; i < 1024; i += 256) dst[i] = src[i];
  }
  for (int idx = t; idx < 32 * 257; idx += 256) {
    int kd = idx / 257, jo = idx % 257;
    cols_s[kd * 260 + jo] = colsT[idx];
  }
  if (t < 32) bv_s[t] = bv[t];
  __syncthreads();

  int row = blockIdx.x * 256 + t;
  if (row >= n) return;

  // ---- phase 1: desc[32] = feats[row] @ Wv + bv (in registers)
  float d[32];
#pragma unroll
  for (int k = 0; k < 32; ++k) d[k] = bv_s[k];
  const float* fr = feats + (size_t)row * 128;
  for (int c0 = 0; c0 < 128; c0 += 16) {
    // one full 64B line per lane
    float4 f0 = *(const float4*)(fr + c0);
    float4 f1 = *(const float4*)(fr + c0 + 4);
    float4 f2 = *(const float4*)(fr + c0 + 8);
    float4 f3 = *(const float4*)(fr + c0 + 12);
    float fs[16] = {f0.x, f0.y, f0.z, f0.w, f1.x, f1.y, f1.z, f1.w,
                    f2.x, f2.y, f2.z, f2.w, f3.x, f3.y, f3.z, f3.w};
#pragma unroll
    for (int cc = 0; cc < 16; ++cc) {
      float f = fs[cc];
      const float* wr = &Wv_s[(c0 + cc) * 32];
      float4 w0 = *(const float4*)(wr + 0);
      float4 w1 = *(const float4*)(wr + 4);
      float4 w2 = *(const float4*)(wr + 8);
      float4 w3 = *(const float4*)(wr + 12);
      float4 w4 = *(const float4*)(wr + 16);
      float4 w5 = *(const float4*)(wr + 20);
      float4 w6 = *(const float4*)(wr + 24);
      float4 w7 = *(const float4*)(wr + 28);
      d[0] += f * w0.x; d[1] += f * w0.y; d[2] += f * w0.z; d[3] += f * w0.w;
      d[4] += f * w1.x; d[5] += f * w1.y; d[6] += f * w1.z; d[7] += f * w1.w;
      d[8] += f * w2.x; d[9] += f * w2.y; d[10] += f * w2.z; d[11] += f * w2.w;
      d[12] += f * w3.x; d[13] += f * w3.y; d[14] += f * w3.z; d[15] += f * w3.w;
      d[16] += f * w4.x; d[17] += f * w4.y; d[18] += f * w4.z; d[19] += f * w4.w;
      d[20] += f * w5.x; d[21] += f * w5.y; d[22] += f * w5.z; d[23] += f * w5.w;
      d[24] += f * w6.x; d[25] += f * w6.y; d[26] += f * w6.z; d[27] += f * w6.w;
      d[28] += f * w7.x; d[29] += f * w7.y; d[30] += f * w7.z; d[31] += f * w7.w;
    }
  }

  // ---- phase 2: out[row] = d @ cols (row-contiguous stores, L2 combines)
  float* op = out + 256 + (size_t)row * 257;
  for (int j0 = 0; j0 < 256; j0 += 8) {
    float acc[8];
#pragma unroll
    for (int j = 0; j < 8; ++j) acc[j] = 0.f;
#pragma unroll
    for (int k = 0; k < 32; ++k) {
      float f = d[k];
      float4 cA = *(const float4*)&cols_s[k * 260 + j0];
      float4 cB = *(const float4*)&cols_s[k * 260 + j0 + 4];
      acc[0] += f * cA.x; acc[1] += f * cA.y; acc[2] += f * cA.z; acc[3] += f * cA.w;
      acc[4] += f * cB.x; acc[5] += f * cB.y; acc[6] += f * cB.z; acc[7] += f * cB.w;
    }
#pragma unroll
    for (int j = 0; j < 8; ++j) op[j0 + j] = acc[j];
  }
  // tail column jo = 256
  {
    float accT = 0.f;
#pragma unroll
    for (int k = 0; k < 32; ++k) accT += d[k] * cols_s[k * 260 + 256];
    op[256] = accT;
  }
}

// ---------------------------------------------------------------------------
extern "C" void kernel_launch(void* const* d_in, const int* in_sizes, int n_in,
                              void* d_out, int out_size, void* d_ws, size_t ws_size,
                              hipStream_t stream) {
  const int*   coords = (const int*)d_in[0];
  const float* feats  = (const float*)d_in[1];
  const float* scores = (const float*)d_in[2];
  const float* Wv     = (const float*)d_in[3];
  const float* bv     = (const float*)d_in[4];
  const float* Wc     = (const float*)d_in[5];
  const float* bc     = (const float*)d_in[6];
  const float* bg     = (const float*)d_in[7];
  float* out = (float*)d_out;
  int n = in_sizes[0] / 4;

  char* ws = (char*)d_ws;
  size_t off = 0;
  auto alloc = [&](size_t bytes) -> char* {
    char* p = ws + off;
    off = (off + bytes + 255) & ~(size_t)255;
    return p;
  };
  // 0xFF region (contiguous from ws start): table + owner_init
  int*   table      = (int*)alloc((size_t)TABLE_N * 4);
  int*   owner_init = (int*)alloc((size_t)n * 4);
  size_t ff_bytes   = off;
  int*   keys       = (int*)alloc((size_t)n * 4);
  // zero region (contiguous)
  char*  zero_base  = ws + off;
  int*   visited    = (int*)alloc((size_t)n * 4);
  int*   cand_cnt   = (int*)alloc(256);
  int*   hist       = (int*)alloc(2048 * 4);
  float* sums       = (float*)alloc(256 * 128 * 4);
  float* counts     = (float*)alloc(256 * 4);
  size_t zero_bytes = (size_t)((ws + off) - zero_base);
  uint2* cand       = (uint2*)alloc((size_t)n * 8);
  int*   peak_vox   = (int*)alloc(KTOP * 4);
  float* colsT      = (float*)alloc(32 * 257 * 4);
  (void)ws_size;

  hipMemsetAsync(table, 0xFF, ff_bytes, stream);
  hipMemsetAsync(zero_base, 0, zero_bytes, stream);

  int nb = (n + 255) / 256;
  k_build<<<nb, 256, 0, stream>>>(coords, table, keys, n);
  k_peak<<<nb, 256, 0, stream>>>(scores, keys, table, cand, cand_cnt, hist, n);
  k_select<<<1, 1024, 0, stream>>>(cand, cand_cnt, hist, out, owner_init, peak_vox);
  k_owner<<<7, 256, 0, stream>>>(scores, keys, table, owner_init, peak_vox,
                                 visited, feats, sums, counts);
  k_cols<<<(32 * 257 + 255) / 256, 256, 0, stream>>>(sums, counts, out, Wc, bc, bg, colsT);
  k_rows<<<nb, 256, 0, stream>>>(feats, Wv, bv, colsT, out, n);
}